// Round 1
// baseline (134.702 us; speedup 1.0000x reference)
//
#include <hip/hip_runtime.h>

// VQC 12-qubit statevector sim, batch=1024.
// One wave (64 lanes) per batch element. Full state (4096 complex) lives in
// registers: re[64], im[64] per lane. Flat index i: bit p <-> qubit (11-p).
// lane = bits[5:0] (qubits 11..6), reg r = bits[11:6] (qubits 5..0).

#define PI_F 3.14159265358979323846f

// ---- Y**t gate (U = [[c,-s],[s,c]], a = pi*t/2) on qubit with flat-bit P ----
template<int P>
__device__ __forceinline__ void ypow_gate(float (&re)[64], float (&im)[64],
                                          int lane, float c, float s) {
    if constexpr (P >= 6) {
        constexpr int rb = P - 6;
        #pragma unroll
        for (int r0 = 0; r0 < 64; ++r0) {
            if ((r0 >> rb) & 1) continue;
            const int r1 = r0 | (1 << rb);
            float a0r = re[r0], a0i = im[r0];
            float a1r = re[r1], a1i = im[r1];
            re[r0] = c * a0r - s * a1r;  im[r0] = c * a0i - s * a1i;
            re[r1] = s * a0r + c * a1r;  im[r1] = s * a0i + c * a1i;
        }
    } else {
        const int bit = (lane >> P) & 1;
        const float ss = bit ? s : -s;   // bit0: c*mine - s*partner; bit1: c*mine + s*partner
        #pragma unroll
        for (int r = 0; r < 64; ++r) {
            float pr = __shfl_xor(re[r], 1 << P, 64);
            float pi = __shfl_xor(im[r], 1 << P, 64);
            re[r] = c * re[r] + ss * pr;
            im[r] = c * im[r] + ss * pi;
        }
    }
}

// ---- Z**t gate (diag(1, e^{i*pi*t})) on qubit with flat-bit P ----
template<int P>
__device__ __forceinline__ void zpow_gate(float (&re)[64], float (&im)[64],
                                          int lane, float pc, float ps) {
    if constexpr (P >= 6) {
        constexpr int rb = P - 6;
        #pragma unroll
        for (int r = 0; r < 64; ++r) {
            if (!((r >> rb) & 1)) continue;
            float nr = pc * re[r] - ps * im[r];
            float ni = ps * re[r] + pc * im[r];
            re[r] = nr; im[r] = ni;
        }
    } else {
        const int bit = (lane >> P) & 1;
        const float c2 = bit ? pc : 1.0f;
        const float s2 = bit ? ps : 0.0f;
        #pragma unroll
        for (int r = 0; r < 64; ++r) {
            float nr = c2 * re[r] - s2 * im[r];
            float ni = s2 * re[r] + c2 * im[r];
            re[r] = nr; im[r] = ni;
        }
    }
}

// ---- CNOT, control flat-bit PC, target flat-bit PT (= PC-1 in this circuit) ----
template<int PC, int PT>
__device__ __forceinline__ void cnot_gate(float (&re)[64], float (&im)[64], int lane) {
    if constexpr (PC >= 7) {
        // both bits in register index: pure swap (copy-prop after unroll)
        constexpr int cb = PC - 6, tb = PT - 6;
        #pragma unroll
        for (int r = 0; r < 64; ++r) {
            if (((r >> cb) & 1) && !((r >> tb) & 1)) {
                const int r2 = r | (1 << tb);
                float t;
                t = re[r]; re[r] = re[r2]; re[r2] = t;
                t = im[r]; im[r] = im[r2]; im[r2] = t;
            }
        }
    } else if constexpr (PC == 6) {
        // control = reg bit 0, target = lane bit 5: swap across lane^32 for odd r
        #pragma unroll
        for (int r = 1; r < 64; r += 2) {
            re[r] = __shfl_xor(re[r], 32, 64);
            im[r] = __shfl_xor(im[r], 32, 64);
        }
    } else {
        // both bits in lane index
        const int ctrl = (lane >> PC) & 1;
        #pragma unroll
        for (int r = 0; r < 64; ++r) {
            float pr = __shfl_xor(re[r], 1 << PT, 64);
            float pi = __shfl_xor(im[r], 1 << PT, 64);
            re[r] = ctrl ? pr : re[r];
            im[r] = ctrl ? pi : im[r];
        }
    }
}

// ---- one ansatz layer: Y**th[q,0], Z**th[q,1] per qubit (compile-time unrolled) ----
template<int Q>
__device__ __forceinline__ void ansatz_qubits(float (&re)[64], float (&im)[64],
                                              int lane, const float* __restrict__ th) {
    if constexpr (Q < 12) {
        constexpr int P = 11 - Q;
        const float ty = th[Q * 2 + 0];
        const float tz = th[Q * 2 + 1];
        float ys, yc; __sincosf(0.5f * PI_F * ty, &ys, &yc);
        float zs, zc; __sincosf(PI_F * tz, &zs, &zc);
        ypow_gate<P>(re, im, lane, yc, ys);
        zpow_gate<P>(re, im, lane, zc, zs);
        ansatz_qubits<Q + 1>(re, im, lane, th);
    }
}

template<int Q>
__device__ __forceinline__ void cnot_chain(float (&re)[64], float (&im)[64], int lane) {
    if constexpr (Q < 11) {
        cnot_gate<11 - Q, 10 - Q>(re, im, lane);
        cnot_chain<Q + 1>(re, im, lane);
    }
}

__global__ __launch_bounds__(64) void vqc_kernel(
    const float* __restrict__ inputs,   // [1024,12]
    const float* __restrict__ thetas,   // [72] = [3][12][2]
    float* __restrict__ out)            // [1024,12]
{
    const int b = blockIdx.x;
    const int lane = threadIdx.x;       // 0..63
    const float* x = inputs + b * 12;

    float re[64], im[64];

    // ---- Encoding block, closed form:
    // amp_i = 2^-6 * exp(i*pi * sum_{q: bit_q(i)=1} x_q)
    float xr[6], xl[6];
    #pragma unroll
    for (int i = 0; i < 6; ++i) { xr[i] = x[5 - i]; xl[i] = x[11 - i]; }

    float lanePhase = 0.0f;
    #pragma unroll
    for (int lb = 0; lb < 6; ++lb)
        lanePhase += ((lane >> lb) & 1) ? xl[lb] : 0.0f;

    #pragma unroll
    for (int r = 0; r < 64; ++r) {
        float ph = lanePhase;
        #pragma unroll
        for (int rb = 0; rb < 6; ++rb)
            if ((r >> rb) & 1) ph += xr[rb];
        float sa, ca;
        __sincosf(PI_F * ph, &sa, &ca);
        re[r] = ca * 0.015625f;   // 1/64
        im[r] = sa * 0.015625f;
    }

    // ---- 3 ansatz layers (layers 0,1 with CNOT chain; layer 2 without)
    #pragma unroll 1
    for (int l = 0; l < 3; ++l) {
        ansatz_qubits<0>(re, im, lane, thetas + l * 24);
        if (l < 2) cnot_chain<0>(re, im, lane);
    }

    // ---- Readout: <Z_q> = sum_i |amp_i|^2 * (+1 if bit_{11-q}(i)==0 else -1)
    float totalP = 0.0f;
    float D[6] = {0, 0, 0, 0, 0, 0};
    #pragma unroll
    for (int r = 0; r < 64; ++r) {
        const float p = re[r] * re[r] + im[r] * im[r];
        totalP += p;
        #pragma unroll
        for (int rb = 0; rb < 6; ++rb)
            D[rb] += ((r >> rb) & 1) ? -p : p;
    }

    #pragma unroll
    for (int q = 0; q < 12; ++q) {
        float v;
        if (q <= 5) {
            v = D[5 - q];                         // register-bit qubit: rb = 5-q
        } else {
            const int lb = 11 - q;                // lane-bit qubit
            v = ((lane >> lb) & 1) ? -totalP : totalP;
        }
        #pragma unroll
        for (int off = 32; off >= 1; off >>= 1)
            v += __shfl_xor(v, off, 64);
        if (lane == 0) out[b * 12 + q] = v;
    }
}

extern "C" void kernel_launch(void* const* d_in, const int* in_sizes, int n_in,
                              void* d_out, int out_size, void* d_ws, size_t ws_size,
                              hipStream_t stream) {
    const float* inputs = (const float*)d_in[0];   // [1024,12] f32
    const float* thetas = (const float*)d_in[1];   // [72] f32
    float* out = (float*)d_out;                    // [1024,12] f32
    vqc_kernel<<<dim3(1024), dim3(64), 0, stream>>>(inputs, thetas, out);
}

// Round 2
// 106.516 us; speedup vs baseline: 1.2646x; 1.2646x over previous
//
#include <hip/hip_runtime.h>

// VQC 12-qubit statevector, batch=1024.
// TWO waves per batch element (block=128): flat index i (12 bits):
//   bit 11 (qubit 0)   = wave id w
//   bits [10:6] (q1..5)= register index r (5 bits, 32 complex regs/lane)
//   bits [5:0] (q6..11)= lane (qubit q <-> lane bit 11-q)
// Qubit-0 gates: Y needs a cross-wave LDS exchange (3x total); Z is diagonal
// (wave-local phase). Layer Zs fused (commuting); last layer's Zs are no-ops
// for the |amp|^2 readout and are skipped entirely.

#define PI_F 3.14159265358979323846f
#define NR 32

template<int RB>
__device__ __forceinline__ void ypow_reg(float (&re)[NR], float (&im)[NR], float c, float s) {
    #pragma unroll
    for (int r0 = 0; r0 < NR; ++r0) {
        if ((r0 >> RB) & 1) continue;
        const int r1 = r0 | (1 << RB);
        float a0r = re[r0], a0i = im[r0];
        float a1r = re[r1], a1i = im[r1];
        re[r0] = c * a0r - s * a1r;  im[r0] = c * a0i - s * a1i;
        re[r1] = s * a0r + c * a1r;  im[r1] = s * a0i + c * a1i;
    }
}

template<int LB>
__device__ __forceinline__ void ypow_lane(float (&re)[NR], float (&im)[NR], int lane, float c, float s) {
    const float ss = ((lane >> LB) & 1) ? s : -s;
    #pragma unroll
    for (int r = 0; r < NR; ++r) {
        float pr = __shfl_xor(re[r], 1 << LB, 64);
        float pi = __shfl_xor(im[r], 1 << LB, 64);
        re[r] = c * re[r] + ss * pr;
        im[r] = c * im[r] + ss * pi;
    }
}

__device__ __forceinline__ void ypow_wave(float (&re)[NR], float (&im)[NR],
                                          float2* xbuf, int w, int lane,
                                          float c, float s) {
    __syncthreads();                       // buffer safe to overwrite
    #pragma unroll
    for (int r = 0; r < NR; ++r)
        xbuf[(w * NR + r) * 64 + lane] = make_float2(re[r], im[r]);
    __syncthreads();
    const float ss = w ? s : -s;           // w0: c*a0 - s*a1 ; w1: c*a1 + s*a0
    #pragma unroll
    for (int r = 0; r < NR; ++r) {
        float2 p = xbuf[((1 - w) * NR + r) * 64 + lane];
        re[r] = c * re[r] + ss * p.x;
        im[r] = c * im[r] + ss * p.y;
    }
}

template<int RB>
__device__ __forceinline__ void zpow_reg(float (&re)[NR], float (&im)[NR], float pc, float ps) {
    #pragma unroll
    for (int r = 0; r < NR; ++r) {
        if (!((r >> RB) & 1)) continue;
        float nr = pc * re[r] - ps * im[r];
        float ni = ps * re[r] + pc * im[r];
        re[r] = nr; im[r] = ni;
    }
}

template<int CB, int TB>
__device__ __forceinline__ void cnot_rr(float (&re)[NR], float (&im)[NR]) {
    #pragma unroll
    for (int r = 0; r < NR; ++r) {
        if (((r >> CB) & 1) && !((r >> TB) & 1)) {
            const int r2 = r | (1 << TB);
            float t;
            t = re[r]; re[r] = re[r2]; re[r2] = t;
            t = im[r]; im[r] = im[r2]; im[r2] = t;
        }
    }
}

template<int CB, int TB>
__device__ __forceinline__ void cnot_ll(float (&re)[NR], float (&im)[NR], int lane) {
    const int ctrl = (lane >> CB) & 1;
    #pragma unroll
    for (int r = 0; r < NR; ++r) {
        float pr = __shfl_xor(re[r], 1 << TB, 64);
        float pi = __shfl_xor(im[r], 1 << TB, 64);
        re[r] = ctrl ? pr : re[r];
        im[r] = ctrl ? pi : im[r];
    }
}

__global__ __launch_bounds__(128) void vqc_kernel(
    const float* __restrict__ inputs,   // [1024,12]
    const float* __restrict__ thetas,   // [72] = [3][12][2]
    float* __restrict__ out)            // [1024,12]
{
    __shared__ float2 xbuf[2 * NR * 64];   // 32 KB exchange buffer
    __shared__ float redBuf[24];

    const int b = blockIdx.x;
    const int tid = threadIdx.x;
    const int w = tid >> 6;                // wave id = flat bit 11 = qubit 0
    const int lane = tid & 63;
    const float* x = inputs + b * 12;

    float re[NR], im[NR];

    // ---- Encoding, closed form: amp_i = 2^-6 * exp(i*pi*sum_{q set} x_q)
    float base = w ? x[0] : 0.0f;
    #pragma unroll
    for (int lb = 0; lb < 6; ++lb)
        base += ((lane >> lb) & 1) ? x[11 - lb] : 0.0f;
    float xr[5];
    #pragma unroll
    for (int rb = 0; rb < 5; ++rb) xr[rb] = x[5 - rb];

    #pragma unroll
    for (int r = 0; r < NR; ++r) {
        float ph = base;
        #pragma unroll
        for (int rb = 0; rb < 5; ++rb)
            if ((r >> rb) & 1) ph += xr[rb];
        float sa, ca;
        __sincosf(PI_F * ph, &sa, &ca);
        re[r] = ca * 0.015625f;   // 1/64
        im[r] = sa * 0.015625f;
    }

    // ---- 3 ansatz layers
    #pragma unroll 1
    for (int l = 0; l < 3; ++l) {
        const float* th = thetas + l * 24;

        // All 12 Y gates (distinct-qubit single-qubit gates commute; each
        // Y_q still precedes its own Z_q below).
        { float s_, c_; __sincosf(0.5f * PI_F * th[0],      &s_, &c_); ypow_wave(re, im, xbuf, w, lane, c_, s_); }
        { float s_, c_; __sincosf(0.5f * PI_F * th[2 * 1],  &s_, &c_); ypow_reg<4>(re, im, c_, s_); }
        { float s_, c_; __sincosf(0.5f * PI_F * th[2 * 2],  &s_, &c_); ypow_reg<3>(re, im, c_, s_); }
        { float s_, c_; __sincosf(0.5f * PI_F * th[2 * 3],  &s_, &c_); ypow_reg<2>(re, im, c_, s_); }
        { float s_, c_; __sincosf(0.5f * PI_F * th[2 * 4],  &s_, &c_); ypow_reg<1>(re, im, c_, s_); }
        { float s_, c_; __sincosf(0.5f * PI_F * th[2 * 5],  &s_, &c_); ypow_reg<0>(re, im, c_, s_); }
        { float s_, c_; __sincosf(0.5f * PI_F * th[2 * 6],  &s_, &c_); ypow_lane<5>(re, im, lane, c_, s_); }
        { float s_, c_; __sincosf(0.5f * PI_F * th[2 * 7],  &s_, &c_); ypow_lane<4>(re, im, lane, c_, s_); }
        { float s_, c_; __sincosf(0.5f * PI_F * th[2 * 8],  &s_, &c_); ypow_lane<3>(re, im, lane, c_, s_); }
        { float s_, c_; __sincosf(0.5f * PI_F * th[2 * 9],  &s_, &c_); ypow_lane<2>(re, im, lane, c_, s_); }
        { float s_, c_; __sincosf(0.5f * PI_F * th[2 * 10], &s_, &c_); ypow_lane<1>(re, im, lane, c_, s_); }
        { float s_, c_; __sincosf(0.5f * PI_F * th[2 * 11], &s_, &c_); ypow_lane<0>(re, im, lane, c_, s_); }

        if (l < 2) {
            // Fused Z: wave-bit + all 6 lane-bit Z phases -> ONE complex factor
            float zang = w ? th[1] : 0.0f;
            #pragma unroll
            for (int lb = 0; lb < 6; ++lb)
                zang += ((lane >> lb) & 1) ? th[2 * (11 - lb) + 1] : 0.0f;
            float zs, zc; __sincosf(PI_F * zang, &zs, &zc);
            #pragma unroll
            for (int r = 0; r < NR; ++r) {
                float nr = zc * re[r] - zs * im[r];
                float ni = zs * re[r] + zc * im[r];
                re[r] = nr; im[r] = ni;
            }
            // Register-bit Zs (qubits 1..5)
            { float s_, c_; __sincosf(PI_F * th[2 * 1 + 1], &s_, &c_); zpow_reg<4>(re, im, c_, s_); }
            { float s_, c_; __sincosf(PI_F * th[2 * 2 + 1], &s_, &c_); zpow_reg<3>(re, im, c_, s_); }
            { float s_, c_; __sincosf(PI_F * th[2 * 3 + 1], &s_, &c_); zpow_reg<2>(re, im, c_, s_); }
            { float s_, c_; __sincosf(PI_F * th[2 * 4 + 1], &s_, &c_); zpow_reg<1>(re, im, c_, s_); }
            { float s_, c_; __sincosf(PI_F * th[2 * 5 + 1], &s_, &c_); zpow_reg<0>(re, im, c_, s_); }

            // CNOT chain q -> q+1
            // q0->q1: ctrl = wave bit, tgt = reg bit 4 (wave-uniform branch)
            if (w) {
                #pragma unroll
                for (int r = 0; r < 16; ++r) {
                    float t;
                    t = re[r]; re[r] = re[r + 16]; re[r + 16] = t;
                    t = im[r]; im[r] = im[r + 16]; im[r + 16] = t;
                }
            }
            cnot_rr<4, 3>(re, im);   // q1->q2
            cnot_rr<3, 2>(re, im);   // q2->q3
            cnot_rr<2, 1>(re, im);   // q3->q4
            cnot_rr<1, 0>(re, im);   // q4->q5
            // q5->q6: ctrl = reg bit 0, tgt = lane bit 5
            #pragma unroll
            for (int r = 1; r < NR; r += 2) {
                re[r] = __shfl_xor(re[r], 32, 64);
                im[r] = __shfl_xor(im[r], 32, 64);
            }
            cnot_ll<5, 4>(re, im, lane);  // q6->q7
            cnot_ll<4, 3>(re, im, lane);  // q7->q8
            cnot_ll<3, 2>(re, im, lane);  // q8->q9
            cnot_ll<2, 1>(re, im, lane);  // q9->q10
            cnot_ll<1, 0>(re, im, lane);  // q10->q11
        }
        // Last layer: Z gates are diagonal -> no effect on |amp|^2 readout; skipped.
    }

    // ---- Readout: <Z_q> = sum |amp|^2 * sign(bit)
    float totalP = 0.0f;
    float D[5] = {0, 0, 0, 0, 0};
    #pragma unroll
    for (int r = 0; r < NR; ++r) {
        const float p = re[r] * re[r] + im[r] * im[r];
        totalP += p;
        #pragma unroll
        for (int rb = 0; rb < 5; ++rb)
            D[rb] += ((r >> rb) & 1) ? -p : p;
    }

    #pragma unroll
    for (int q = 0; q < 12; ++q) {
        float v;
        if (q == 0)      v = w ? -totalP : totalP;
        else if (q <= 5) v = D[5 - q];
        else             v = ((lane >> (11 - q)) & 1) ? -totalP : totalP;
        #pragma unroll
        for (int off = 32; off >= 1; off >>= 1)
            v += __shfl_xor(v, off, 64);
        if (lane == 0) redBuf[w * 12 + q] = v;
    }
    __syncthreads();
    if (tid < 12) out[b * 12 + tid] = redBuf[tid] + redBuf[12 + tid];
}

extern "C" void kernel_launch(void* const* d_in, const int* in_sizes, int n_in,
                              void* d_out, int out_size, void* d_ws, size_t ws_size,
                              hipStream_t stream) {
    const float* inputs = (const float*)d_in[0];   // [1024,12] f32
    const float* thetas = (const float*)d_in[1];   // [72] f32
    float* out = (float*)d_out;                    // [1024,12] f32
    vqc_kernel<<<dim3(1024), dim3(128), 0, stream>>>(inputs, thetas, out);
}

// Round 3
// 77.163 us; speedup vs baseline: 1.7457x; 1.3804x over previous
//
#include <hip/hip_runtime.h>

// VQC 12-qubit statevector, batch=1024, 2 waves/block (one batch elem/block).
// Flat index i (12 bits), qubit q <-> bit (11-q).
// Layout A: b11=w(q0), b10..b6=reg r(q1..q5), b5..b0=lane(q6..q11)
// Layout B: b11=w(q0), b10..b5=lane(q1..q6),  b4..b0=reg r(q7..q11)
// Per layer: Y q1..5 in-reg [A]; A->B exchange (fuses Y_q6); Y q7..11 in-reg [B];
// fused Z (all 12, Gray-code product); B->A exchange (fuses CNOT-chain
// permutation x = y^(y>>1) AND next layer's Y_q0). Y_q0 of layer 0 is folded
// into the closed-form encoding; last layer's Zs are no-ops for |amp|^2 readout.

#define PI_F 3.14159265358979323846f
#define NR 32
#define PAD 66   // even: keeps b128 pairs 16B-aligned; bank-floor verified

__device__ __forceinline__ float2 cmul(float2 a, float2 b) {
    return make_float2(a.x*b.x - a.y*b.y, a.x*b.y + a.y*b.x);
}
__device__ __forceinline__ float2 cmulc(float2 a, float2 b) {  // a * conj(b)
    return make_float2(a.x*b.x + a.y*b.y, a.y*b.x - a.x*b.y);
}

template<int RB>
__device__ __forceinline__ void ypow_reg(float2 (&a)[NR], float c, float s) {
    #pragma unroll
    for (int r0 = 0; r0 < NR; ++r0) {
        if ((r0 >> RB) & 1) continue;
        const int r1 = r0 | (1 << RB);
        float2 a0 = a[r0], a1 = a[r1];
        a[r0] = make_float2(c*a0.x - s*a1.x, c*a0.y - s*a1.y);
        a[r1] = make_float2(s*a0.x + c*a1.x, s*a0.y + c*a1.y);
    }
}

// A->B transpose, fusing Y on q6 (b5). Wave-local (b11 untouched).
__device__ __forceinline__ void exchange_AB(float2 (&a)[NR], float2* buf,
                                            int w, int lane, float c6, float s6) {
    float2* wb = buf + w * (NR * PAD);
    __syncthreads();                       // buffer free from previous reads
    #pragma unroll
    for (int r = 0; r < NR; ++r)           // slot = [b10..b6 | b4..b0 | b5]
        wb[r * PAD + (lane & 31) * 2 + (lane >> 5)] = a[r];
    __syncthreads();
    const int g = lane >> 1;               // b10..b6 of output
    const float k0 = (lane & 1) ? s6 : c6;
    const float k1 = (lane & 1) ? c6 : -s6;
    #pragma unroll
    for (int r = 0; r < NR; ++r) {
        float2 p0 = wb[g * PAD + r * 2];       // b5 = 0
        float2 p1 = wb[g * PAD + r * 2 + 1];   // b5 = 1
        a[r] = make_float2(k0*p0.x + k1*p1.x, k0*p0.y + k1*p1.y);
    }
}

// B->A transpose, fusing the CNOT-chain permutation (new[y] = old[y ^ (y>>1)])
// and the NEXT layer's Y_q0 (mixes b11; flipping b11 of y flips bits 11,10 of x,
// so pairs share (x10^x11, x9..x0) and are stored adjacent).
__device__ __forceinline__ void exchange_BA(float2 (&a)[NR], float2* buf,
                                            int w, int lane, float c0, float s0) {
    __syncthreads();
    const int p6w = lane ^ (w << 5);       // (x10^x11)<<5 | x9..x5 for this writer
    #pragma unroll
    for (int r = 0; r < NR; ++r)           // slot = p6*PAD + (x4..x0)*2 + x11
        buf[p6w * PAD + r * 2 + w] = a[r];
    __syncthreads();
    const float k0 = w ? s0 : c0;
    const float k1 = w ? c0 : -s0;
    #pragma unroll
    for (int rp = 0; rp < NR; ++rp) {
        const int ylow = (rp << 6) | lane;         // b10..b0 of output index
        const int t = ylow ^ (ylow >> 1);          // Gray inverse (11 bits)
        const int base = (t >> 5) * PAD + (t & 31) * 2;
        float2 p0 = buf[base];                     // input b11 = 0
        float2 p1 = buf[base + 1];                 // input b11 = 1
        a[rp] = make_float2(k0*p0.x + k1*p1.x, k0*p0.y + k1*p1.y);
    }
}

__device__ __forceinline__ void ypow_block_regA(float2 (&a)[NR], const float* __restrict__ th) {
    // q1..q5 -> reg bits 4..0 (layout A); y-angle = 0.5*pi*th[2q]
    { float s,c; __sincosf(0.5f*PI_F*th[2],  &s,&c); ypow_reg<4>(a,c,s); }
    { float s,c; __sincosf(0.5f*PI_F*th[4],  &s,&c); ypow_reg<3>(a,c,s); }
    { float s,c; __sincosf(0.5f*PI_F*th[6],  &s,&c); ypow_reg<2>(a,c,s); }
    { float s,c; __sincosf(0.5f*PI_F*th[8],  &s,&c); ypow_reg<1>(a,c,s); }
    { float s,c; __sincosf(0.5f*PI_F*th[10], &s,&c); ypow_reg<0>(a,c,s); }
}
__device__ __forceinline__ void ypow_block_regB(float2 (&a)[NR], const float* __restrict__ th) {
    // q7..q11 -> reg bits 4..0 (layout B)
    { float s,c; __sincosf(0.5f*PI_F*th[14], &s,&c); ypow_reg<4>(a,c,s); }
    { float s,c; __sincosf(0.5f*PI_F*th[16], &s,&c); ypow_reg<3>(a,c,s); }
    { float s,c; __sincosf(0.5f*PI_F*th[18], &s,&c); ypow_reg<2>(a,c,s); }
    { float s,c; __sincosf(0.5f*PI_F*th[20], &s,&c); ypow_reg<1>(a,c,s); }
    { float s,c; __sincosf(0.5f*PI_F*th[22], &s,&c); ypow_reg<0>(a,c,s); }
}

// Fused Z for all 12 qubits, state in layout B. Per-amp factor built as a
// Gray-code running complex product (1 sincos for the lane/wave part).
__device__ __forceinline__ void fused_z_B(float2 (&a)[NR], int w, int lane,
                                          const float* __restrict__ th) {
    float alpha = w ? th[1] : 0.0f;
    #pragma unroll
    for (int k = 0; k < 6; ++k)                 // lane bit k <-> q(6-k)
        alpha += ((lane >> k) & 1) ? th[2*(6-k)+1] : 0.0f;
    float2 zb; __sincosf(PI_F * alpha, &zb.y, &zb.x);
    float2 zq[5];
    #pragma unroll
    for (int j = 0; j < 5; ++j)                 // reg bit j <-> q(11-j)
        __sincosf(PI_F * th[2*(11-j)+1], &zq[j].y, &zq[j].x);
    float2 cur = zb;
    a[0] = cmul(a[0], cur);
    #pragma unroll
    for (int k = 1; k < NR; ++k) {
        const int bit = __builtin_ctz(k);
        const int g = k ^ (k >> 1);
        cur = ((g >> bit) & 1) ? cmul(cur, zq[bit]) : cmulc(cur, zq[bit]);
        a[g] = cmul(a[g], cur);
    }
}

__global__ __launch_bounds__(128) void vqc_kernel(
    const float* __restrict__ inputs,   // [1024,12]
    const float* __restrict__ thetas,   // [72] = [3][12][2]
    float* __restrict__ out)            // [1024,12]
{
    __shared__ __align__(16) float2 buf[64 * PAD];   // 33,792 B exchange buffer
    __shared__ float redBuf[24];

    const int b = blockIdx.x;
    const int tid = threadIdx.x;
    const int w = tid >> 6;
    const int lane = tid & 63;
    const float* x = inputs + b * 12;

    float2 a[NR];

    // ---- Encoding (closed form) with layer-0 Y_q0 folded in.
    // amp = 2^-6 * Fw * cis(pi*phi_rest), Fw = {c0 - s0*E, s0 + c0*E}, E = cis(pi*x0)
    float phb = 0.0f;
    #pragma unroll
    for (int k = 0; k < 6; ++k)                 // lane bit k <-> q(11-k)
        phb += ((lane >> k) & 1) ? x[11 - k] : 0.0f;
    float2 cisb; __sincosf(PI_F * phb, &cisb.y, &cisb.x);
    float2 E;    __sincosf(PI_F * x[0], &E.y, &E.x);
    float s0, c0; __sincosf(0.5f * PI_F * thetas[0], &s0, &c0);
    float2 Fw = w ? make_float2(s0 + c0 * E.x,  c0 * E.y)
                  : make_float2(c0 - s0 * E.x, -s0 * E.y);
    float2 g0 = cmul(Fw, cisb);
    g0.x *= 0.015625f; g0.y *= 0.015625f;
    float2 zr[5];
    #pragma unroll
    for (int j = 0; j < 5; ++j)                 // layout-A reg bit j <-> q(5-j)
        __sincosf(PI_F * x[5 - j], &zr[j].y, &zr[j].x);
    {
        float2 cur = g0;
        a[0] = cur;
        #pragma unroll
        for (int k = 1; k < NR; ++k) {
            const int bit = __builtin_ctz(k);
            const int g = k ^ (k >> 1);
            cur = ((g >> bit) & 1) ? cmul(cur, zr[bit]) : cmulc(cur, zr[bit]);
            a[g] = cur;
        }
    }

    const float* th0 = thetas;
    const float* th1 = thetas + 24;
    const float* th2 = thetas + 48;

    // ----- layer 0 -----
    ypow_block_regA(a, th0);
    { float s,c; __sincosf(0.5f*PI_F*th0[12], &s,&c); exchange_AB(a, buf, w, lane, c, s); }
    ypow_block_regB(a, th0);
    fused_z_B(a, w, lane, th0);
    { float s,c; __sincosf(0.5f*PI_F*th1[0],  &s,&c); exchange_BA(a, buf, w, lane, c, s); }

    // ----- layer 1 -----
    ypow_block_regA(a, th1);
    { float s,c; __sincosf(0.5f*PI_F*th1[12], &s,&c); exchange_AB(a, buf, w, lane, c, s); }
    ypow_block_regB(a, th1);
    fused_z_B(a, w, lane, th1);
    { float s,c; __sincosf(0.5f*PI_F*th2[0],  &s,&c); exchange_BA(a, buf, w, lane, c, s); }

    // ----- layer 2 (no CNOT; Zs dropped — diagonal before |amp|^2) -----
    ypow_block_regA(a, th2);
    { float s,c; __sincosf(0.5f*PI_F*th2[12], &s,&c); exchange_AB(a, buf, w, lane, c, s); }
    ypow_block_regB(a, th2);

    // ---- Readout in layout B: b11=w(q0), lane bit k<->q(6-k), reg bit j<->q(11-j)
    float totalP = 0.0f;
    float D[5] = {0, 0, 0, 0, 0};
    #pragma unroll
    for (int r = 0; r < NR; ++r) {
        const float p = a[r].x * a[r].x + a[r].y * a[r].y;
        totalP += p;
        #pragma unroll
        for (int j = 0; j < 5; ++j)
            D[j] += ((r >> j) & 1) ? -p : p;
    }
    #pragma unroll
    for (int q = 0; q < 12; ++q) {
        float v;
        if (q == 0)       v = w ? -totalP : totalP;
        else if (q <= 6)  v = ((lane >> (6 - q)) & 1) ? -totalP : totalP;
        else              v = D[11 - q];
        #pragma unroll
        for (int off = 32; off >= 1; off >>= 1)
            v += __shfl_xor(v, off, 64);
        if (lane == 0) redBuf[w * 12 + q] = v;
    }
    __syncthreads();
    if (tid < 12) out[b * 12 + tid] = redBuf[tid] + redBuf[12 + tid];
}

extern "C" void kernel_launch(void* const* d_in, const int* in_sizes, int n_in,
                              void* d_out, int out_size, void* d_ws, size_t ws_size,
                              hipStream_t stream) {
    const float* inputs = (const float*)d_in[0];   // [1024,12] f32
    const float* thetas = (const float*)d_in[1];   // [72] f32
    float* out = (float*)d_out;                    // [1024,12] f32
    vqc_kernel<<<dim3(1024), dim3(128), 0, stream>>>(inputs, thetas, out);
}